// Round 4
// baseline (3775.819 us; speedup 1.0000x reference)
//
#include <hip/hip_runtime.h>
#include <hip/hip_bf16.h>

typedef __hip_bfloat16 bf16;

static __device__ __forceinline__ float b2f(bf16 x) { return __bfloat162float(x); }

constexpr int Bb = 16, Nn = 1024, Cc = 768, Dd = 384;

// out[M,Nd] = A[M,K] @ W[K,Nd] + bias, f32 inputs, fp32 accum, bf16 out.
// TILE 64x64, K-step 16, 256 threads, 4x4 per thread. All dims divide evenly.
__global__ __launch_bounds__(256) void proj_gemm(
    const float* __restrict__ A, const float* __restrict__ W,
    const float* __restrict__ bias, bf16* __restrict__ out,
    int M, int K, int Nd)
{
    __shared__ float As[16][65];
    __shared__ float Bs[16][65];
    const int tid = threadIdx.x;
    const int tx = tid & 15, ty = tid >> 4;
    const int row0 = blockIdx.x * 64, col0 = blockIdx.y * 64;

    float acc[4][4] = {};

    for (int k0 = 0; k0 < K; k0 += 16) {
        {
            const int m = tid >> 2, kq = (tid & 3) * 4;
            const float* p = A + (size_t)(row0 + m) * K + k0 + kq;
#pragma unroll
            for (int j = 0; j < 4; j++) As[kq + j][m] = p[j];
        }
        {
            const int k = tid >> 4, n4 = (tid & 15) * 4;
            const float* p = W + (size_t)(k0 + k) * Nd + col0 + n4;
#pragma unroll
            for (int j = 0; j < 4; j++) Bs[k][n4 + j] = p[j];
        }
        __syncthreads();
#pragma unroll
        for (int k = 0; k < 16; k++) {
            float a[4], bv[4];
#pragma unroll
            for (int j = 0; j < 4; j++) a[j] = As[k][ty * 4 + j];
#pragma unroll
            for (int j = 0; j < 4; j++) bv[j] = Bs[k][tx * 4 + j];
#pragma unroll
            for (int i = 0; i < 4; i++)
#pragma unroll
                for (int j = 0; j < 4; j++) acc[i][j] += a[i] * bv[j];
        }
        __syncthreads();
    }

#pragma unroll
    for (int i = 0; i < 4; i++) {
        const int row = row0 + ty * 4 + i;
#pragma unroll
        for (int j = 0; j < 4; j++) {
            const int col = col0 + tx * 4 + j;
            out[(size_t)row * Nd + col] = __float2bfloat16(acc[i][j] + bias[col]);
        }
    }
}

// One block per (b, n) row. Fuses: theta = x_row @ W_theta + b_theta (f32),
// scores = (theta . phi_m) * adj[b,n,m], softmax over m, O = p @ g,
// final = O @ W_out + b_out + x_row  -> f32 out.
__global__ __launch_bounds__(256) void fused_attn(
    const float* __restrict__ x, const float* __restrict__ adj,
    const float* __restrict__ W_theta, const float* __restrict__ b_theta,
    const bf16* __restrict__ phi, const bf16* __restrict__ g,
    const float* __restrict__ W_out, const float* __restrict__ b_out,
    float* __restrict__ out)
{
    __shared__ float xs[Cc];    // x row, f32
    __shared__ float th[Dd];    // theta row, f32
    __shared__ float s[Nn];     // scores / probs
    __shared__ float Os[Dd];    // attention output row
    __shared__ float red[256];

    const int tid = threadIdx.x;
    const int n = blockIdx.x, b = blockIdx.y;
    const int lane = tid & 63, wave = tid >> 6;
    const size_t row = (size_t)b * Nn + n;      // row in [B*N]
    const size_t baseD = (size_t)b * Nn * Dd;   // batch base for phi/g

    // ---- load x row into LDS
    for (int c = tid; c < Cc; c += 256) xs[c] = x[row * Cc + c];
    __syncthreads();

    // ---- theta[d] = b_theta[d] + sum_c xs[c] * W_theta[c, d]   (f32)
    for (int d = tid; d < Dd; d += 256) {
        float acc = b_theta[d];
#pragma unroll 8
        for (int c = 0; c < Cc; c++) acc += xs[c] * W_theta[(size_t)c * Dd + d];
        th[d] = acc;
    }
    __syncthreads();

    // ---- scores: one dot per wave-iteration, lanes split D=384 into 6 chunks
    for (int m = wave; m < Nn; m += 4) {
        const bf16* prow = phi + baseD + (size_t)m * Dd;
        float partial = 0.f;
#pragma unroll
        for (int j = 0; j < 6; j++) {
            const int d = lane + 64 * j;
            partial += th[d] * b2f(prow[d]);
        }
#pragma unroll
        for (int off = 32; off > 0; off >>= 1) partial += __shfl_down(partial, off);
        if (lane == 0)
            s[m] = partial * adj[(size_t)b * Nn * Nn + (size_t)n * Nn + m];
    }
    __syncthreads();

    // ---- softmax over s[0..1023]
    float mx = -1e30f;
    for (int i = tid; i < Nn; i += 256) mx = fmaxf(mx, s[i]);
    red[tid] = mx; __syncthreads();
    for (int st = 128; st > 0; st >>= 1) {
        if (tid < st) red[tid] = fmaxf(red[tid], red[tid + st]);
        __syncthreads();
    }
    mx = red[0]; __syncthreads();

    float lsum = 0.f;
    for (int i = tid; i < Nn; i += 256) {
        const float e = __expf(s[i] - mx);
        s[i] = e;
        lsum += e;
    }
    red[tid] = lsum; __syncthreads();
    for (int st = 128; st > 0; st >>= 1) {
        if (tid < st) red[tid] += red[tid + st];
        __syncthreads();
    }
    const float inv = 1.0f / red[0];
    __syncthreads();

    // ---- O[d] = inv * sum_m s[m] * g[b,m,d]
    for (int d = tid; d < Dd; d += 256) {
        float acc = 0.f;
#pragma unroll 8
        for (int m = 0; m < Nn; m++) acc += s[m] * b2f(g[baseD + (size_t)m * Dd + d]);
        Os[d] = acc * inv;
    }
    __syncthreads();

    // ---- out[c] = b_out[c] + xs[c] + sum_d Os[d] * W_out[d, c]
    for (int c = tid; c < Cc; c += 256) {
        float acc = b_out[c] + xs[c];
#pragma unroll 8
        for (int d = 0; d < Dd; d++) acc += Os[d] * W_out[(size_t)d * Cc + c];
        out[row * Cc + c] = acc;
    }
}

extern "C" void kernel_launch(void* const* d_in, const int* in_sizes, int n_in,
                              void* d_out, int out_size, void* d_ws, size_t ws_size,
                              hipStream_t stream)
{
    const float* x       = (const float*)d_in[0];
    const float* adj     = (const float*)d_in[1];
    const float* W_theta = (const float*)d_in[2];
    const float* b_theta = (const float*)d_in[3];
    const float* W_phi   = (const float*)d_in[4];
    const float* b_phi   = (const float*)d_in[5];
    const float* W_g     = (const float*)d_in[6];
    const float* b_g     = (const float*)d_in[7];
    const float* W_out   = (const float*)d_in[8];
    const float* b_out   = (const float*)d_in[9];
    float* out = (float*)d_out;

    const int M = Bb * Nn;                      // 16384
    const size_t SZ = (size_t)Bb * Nn * Dd;     // 6291456 elems

    // ws usage: 2 bf16 buffers = 25.17 MB total (ws proven >= 50 MB in R2/R3)
    bf16* phi = (bf16*)d_ws;
    bf16* g   = phi + SZ;

    dim3 blk(256);

    // projections: [16384,768] @ [768,384] -> bf16
    dim3 gproj(M / 64, Dd / 64);
    proj_gemm<<<gproj, blk, 0, stream>>>(x, W_phi, b_phi, phi, M, Cc, Dd);
    proj_gemm<<<gproj, blk, 0, stream>>>(x, W_g, b_g, g, M, Cc, Dd);

    // fused theta + attention + out-projection + residual
    fused_attn<<<dim3(Nn, Bb), blk, 0, stream>>>(
        x, adj, W_theta, b_theta, phi, g, W_out, b_out, out);
}

// Round 5
// 377.222 us; speedup vs baseline: 10.0095x; 10.0095x over previous
//
#include <hip/hip_runtime.h>
#include <hip/hip_bf16.h>

typedef __hip_bfloat16 bf16;
typedef short bf16x8 __attribute__((ext_vector_type(8)));
typedef float f32x4 __attribute__((ext_vector_type(4)));

constexpr int Bb = 16, Nn = 1024, Cc = 768, Dd = 384;

static __device__ __forceinline__ f32x4 mfma16(bf16x8 a, bf16x8 b, f32x4 c) {
    return __builtin_amdgcn_mfma_f32_16x16x32_bf16(a, b, c, 0, 0, 0);
}
static __device__ __forceinline__ short f2b(float v) {
    __hip_bfloat16 h = __float2bfloat16(v);
    return *reinterpret_cast<short*>(&h);
}
static __device__ __forceinline__ float b2f(bf16 x) { return __bfloat162float(x); }
static __device__ __forceinline__ float ldf(const float* p) { return *p; }
static __device__ __forceinline__ float ldf(const bf16* p) { return __bfloat162float(*p); }

// ---------------- transpose + cast: out[n][k] = (bf16) in[k][n] ----------------
__global__ __launch_bounds__(256) void transpose_cast(
    const float* __restrict__ in, bf16* __restrict__ out, int K, int N)
{
    __shared__ float t[32][33];
    const int n0 = blockIdx.x * 32, k0 = blockIdx.y * 32;
    const int tx = threadIdx.x & 31, ty = threadIdx.x >> 5;
#pragma unroll
    for (int i = 0; i < 4; i++)
        t[ty + i * 8][tx] = in[(size_t)(k0 + ty + i * 8) * N + n0 + tx];
    __syncthreads();
#pragma unroll
    for (int i = 0; i < 4; i++)
        out[(size_t)(n0 + ty + i * 8) * K + k0 + tx] = __float2bfloat16(t[tx][ty + i * 8]);
}

// ---------------- MFMA GEMM: C = A[M,K] @ BT[N,K]^T + bias (+epilogue) ---------
// 128x128 tile, BK=32, 256 threads (4 waves, 64x64 each), 16x16x32 bf16 MFMA.
// EPI: 0 = bf16 row-major out; 1 = bf16 gT scatter out[(b*Nout+col)*1024+m];
//      2 = f32 out with +resid.
template <typename TA, int EPI>
__global__ __launch_bounds__(256) void gemm_mfma(
    const TA* __restrict__ A, const bf16* __restrict__ BT,
    const float* __restrict__ bias, const float* __restrict__ resid,
    void* __restrict__ outp, int K, int Nout)
{
    __shared__ short As[128 * 40];
    __shared__ short Bs[128 * 40];
    const int tid = threadIdx.x;
    const int lane = tid & 63, w = tid >> 6;
    const int quad = lane >> 4, c = lane & 15;
    const int row0 = blockIdx.x * 128, col0 = blockIdx.y * 128;
    const int wm = (w & 1) * 64, wn = (w >> 1) * 64;

    const f32x4 fz = {0.f, 0.f, 0.f, 0.f};
    f32x4 acc[4][4];
#pragma unroll
    for (int i = 0; i < 4; i++)
#pragma unroll
        for (int j = 0; j < 4; j++) acc[i][j] = fz;

    for (int k0 = 0; k0 < K; k0 += 32) {
        __syncthreads();
        if (sizeof(TA) == 4) {  // f32 A: load float4, convert, ds_write_b64
            const float* Af = (const float*)A;
#pragma unroll
            for (int u = 0; u < 4; u++) {
                const int id = u * 256 + tid;
                const int r = id >> 3, c4 = (id & 7) * 4;
                const float4 v = *reinterpret_cast<const float4*>(Af + (size_t)(row0 + r) * K + k0 + c4);
                uint2 p;
                p.x = ((unsigned)(unsigned short)f2b(v.y) << 16) | (unsigned short)(unsigned)f2b(v.x);
                p.y = ((unsigned)(unsigned short)f2b(v.w) << 16) | (unsigned short)(unsigned)f2b(v.z);
                *reinterpret_cast<uint2*>(&As[r * 40 + c4]) = p;
            }
        } else {                // bf16 A: 16B copies
            const bf16* Ab = (const bf16*)A;
#pragma unroll
            for (int u = 0; u < 2; u++) {
                const int id = u * 256 + tid;
                const int r = id >> 2, c8 = (id & 3) * 8;
                const uint4 v = *reinterpret_cast<const uint4*>(Ab + (size_t)(row0 + r) * K + k0 + c8);
                *reinterpret_cast<uint4*>(&As[r * 40 + c8]) = v;
            }
        }
#pragma unroll
        for (int u = 0; u < 2; u++) {
            const int id = u * 256 + tid;
            const int r = id >> 2, c8 = (id & 3) * 8;
            const uint4 v = *reinterpret_cast<const uint4*>(BT + (size_t)(col0 + r) * K + k0 + c8);
            *reinterpret_cast<uint4*>(&Bs[r * 40 + c8]) = v;
        }
        __syncthreads();

        bf16x8 af[4], bfr[4];
#pragma unroll
        for (int i = 0; i < 4; i++)
            af[i] = *reinterpret_cast<const bf16x8*>(&As[(wm + i * 16 + c) * 40 + quad * 8]);
#pragma unroll
        for (int j = 0; j < 4; j++)
            bfr[j] = *reinterpret_cast<const bf16x8*>(&Bs[(wn + j * 16 + c) * 40 + quad * 8]);
#pragma unroll
        for (int i = 0; i < 4; i++)
#pragma unroll
            for (int j = 0; j < 4; j++)
                acc[i][j] = mfma16(af[i], bfr[j], acc[i][j]);
    }

#pragma unroll
    for (int i = 0; i < 4; i++) {
        const int rowb = row0 + wm + i * 16 + quad * 4;
#pragma unroll
        for (int j = 0; j < 4; j++) {
            const int col = col0 + wn + j * 16 + c;
            const float bcol = bias[col];
#pragma unroll
            for (int r = 0; r < 4; r++) {
                float v = acc[i][j][r] + bcol;
                const int rr = rowb + r;
                if (EPI == 0) {
                    ((bf16*)outp)[(size_t)rr * Nout + col] = __float2bfloat16(v);
                } else if (EPI == 1) {
                    const int bb = rr >> 10, m = rr & 1023;
                    ((bf16*)outp)[((size_t)(bb * Nout + col)) * 1024 + m] = __float2bfloat16(v);
                } else {
                    v += resid[(size_t)rr * Nout + col];
                    ((float*)outp)[(size_t)rr * Nout + col] = v;
                }
            }
        }
    }
}

// ---------------- flash attention: S=theta@phi^T * adj, softmax, O=P@g --------
// grid (16 q-tiles, 16 batches), 256 threads = 4 waves x 16 Q-rows.
__global__ __launch_bounds__(256) void flash_attn(
    const bf16* __restrict__ theta, const bf16* __restrict__ phi,
    const bf16* __restrict__ gT, const float* __restrict__ adj,
    bf16* __restrict__ O)
{
    __shared__ short phs[32 * 392];       // phi chunk [32 n][384 d], pad row 392
    __shared__ short gts[384 * 40];       // gT chunk [384 d][32 m], pad row 40
    __shared__ short pls[4][16 * 40];     // per-wave P tile [16 m][32 k], pad 40

    const int tid = threadIdx.x;
    const int lane = tid & 63, w = tid >> 6;
    const int quad = lane >> 4, c = lane & 15;
    const int qb = blockIdx.x, b = blockIdx.y;

    // preload theta A-frags: 16 q-rows x 384 d per wave
    const size_t thbase = ((size_t)b * Nn + qb * 64 + w * 16 + c) * Dd;
    bf16x8 ath[12];
#pragma unroll
    for (int dq = 0; dq < 12; dq++)
        ath[dq] = *reinterpret_cast<const bf16x8*>(theta + thbase + dq * 32 + quad * 8);

    const f32x4 fz = {0.f, 0.f, 0.f, 0.f};
    f32x4 o[24];
#pragma unroll
    for (int t = 0; t < 24; t++) o[t] = fz;
    float mrow[4], lrow[4];
#pragma unroll
    for (int r = 0; r < 4; r++) { mrow[r] = -INFINITY; lrow[r] = 0.f; }

    for (int n0 = 0; n0 < Nn; n0 += 32) {
        __syncthreads();
        {   // stage phi rows n0..n0+31 (32 x 384 bf16 = 1536 16B chunks)
            const bf16* src = phi + ((size_t)b * Nn + n0) * Dd;
#pragma unroll
            for (int u = 0; u < 6; u++) {
                const int id = u * 256 + tid;
                const int r = id / 48, cc = (id % 48) * 8;
                const uint4 v = *reinterpret_cast<const uint4*>(src + (size_t)r * Dd + cc);
                *reinterpret_cast<uint4*>(&phs[r * 392 + cc]) = v;
            }
        }
        {   // stage gT[b][d][n0..n0+31] (384 x 32 bf16 = 1536 16B chunks)
            const bf16* src = gT + ((size_t)b * Dd) * Nn + n0;
#pragma unroll
            for (int u = 0; u < 6; u++) {
                const int id = u * 256 + tid;
                const int r = id >> 2, cc = (id & 3) * 8;
                const uint4 v = *reinterpret_cast<const uint4*>(src + (size_t)r * Nn + cc);
                *reinterpret_cast<uint4*>(&gts[r * 40 + cc]) = v;
            }
        }
        __syncthreads();

        // S tiles: 16 q x 32 n, accumulate over D=384
        f32x4 s0 = fz, s1 = fz;
#pragma unroll
        for (int dq = 0; dq < 12; dq++) {
            const bf16x8 b0 = *reinterpret_cast<const bf16x8*>(&phs[c * 392 + dq * 32 + quad * 8]);
            const bf16x8 b1 = *reinterpret_cast<const bf16x8*>(&phs[(16 + c) * 392 + dq * 32 + quad * 8]);
            s0 = mfma16(ath[dq], b0, s0);
            s1 = mfma16(ath[dq], b1, s1);
        }

        // adj multiply + online softmax (C layout: row = quad*4+r, col = c)
        const float* arow = adj + ((size_t)b * Nn + qb * 64 + w * 16 + quad * 4) * Nn + n0;
        float p0[4], p1[4], alpha[4];
#pragma unroll
        for (int r = 0; r < 4; r++) {
            const float v0 = s0[r] * arow[(size_t)r * Nn + c];
            const float v1 = s1[r] * arow[(size_t)r * Nn + 16 + c];
            float t = fmaxf(v0, v1);
#pragma unroll
            for (int msk = 1; msk < 16; msk <<= 1) t = fmaxf(t, __shfl_xor(t, msk));
            const float mn = fmaxf(mrow[r], t);
            alpha[r] = __expf(mrow[r] - mn);
            mrow[r] = mn;
            p0[r] = __expf(v0 - mn);
            p1[r] = __expf(v1 - mn);
            float u = p0[r] + p1[r];
#pragma unroll
            for (int msk = 1; msk < 16; msk <<= 1) u += __shfl_xor(u, msk);
            lrow[r] = lrow[r] * alpha[r] + u;
        }
#pragma unroll
        for (int t = 0; t < 24; t++)
#pragma unroll
            for (int r = 0; r < 4; r++) o[t][r] *= alpha[r];

        // P (C layout) -> LDS -> A layout
        short* pl = (short*)pls[w];
#pragma unroll
        for (int r = 0; r < 4; r++) {
            pl[(quad * 4 + r) * 40 + c] = f2b(p0[r]);
            pl[(quad * 4 + r) * 40 + 16 + c] = f2b(p1[r]);
        }
        __syncthreads();
        const bf16x8 ap = *reinterpret_cast<const bf16x8*>(&pl[c * 40 + quad * 8]);
#pragma unroll
        for (int dn = 0; dn < 24; dn++) {
            const bf16x8 bg = *reinterpret_cast<const bf16x8*>(&gts[(dn * 16 + c) * 40 + quad * 8]);
            o[dn] = mfma16(ap, bg, o[dn]);
        }
    }

    float inv[4];
#pragma unroll
    for (int r = 0; r < 4; r++) inv[r] = 1.0f / lrow[r];
    bf16* orow = O + ((size_t)b * Nn + qb * 64 + w * 16 + quad * 4) * Dd;
#pragma unroll
    for (int dn = 0; dn < 24; dn++)
#pragma unroll
        for (int r = 0; r < 4; r++)
            orow[(size_t)r * Dd + dn * 16 + c] = __float2bfloat16(o[dn][r] * inv[r]);
}

// ================== fallback path (round-4, proven, needs 25.2 MB ws) =========
__global__ __launch_bounds__(256) void proj_gemm(
    const float* __restrict__ A, const float* __restrict__ W,
    const float* __restrict__ bias, bf16* __restrict__ out,
    int M, int K, int Nd)
{
    __shared__ float Asm[16][65];
    __shared__ float Bsm[16][65];
    const int tid = threadIdx.x;
    const int tx = tid & 15, ty = tid >> 4;
    const int row0 = blockIdx.x * 64, col0 = blockIdx.y * 64;
    float acc[4][4] = {};
    for (int k0 = 0; k0 < K; k0 += 16) {
        {
            const int m = tid >> 2, kq = (tid & 3) * 4;
            const float* p = A + (size_t)(row0 + m) * K + k0 + kq;
#pragma unroll
            for (int j = 0; j < 4; j++) Asm[kq + j][m] = p[j];
        }
        {
            const int k = tid >> 4, n4 = (tid & 15) * 4;
            const float* p = W + (size_t)(k0 + k) * Nd + col0 + n4;
#pragma unroll
            for (int j = 0; j < 4; j++) Bsm[k][n4 + j] = p[j];
        }
        __syncthreads();
#pragma unroll
        for (int k = 0; k < 16; k++) {
            float a[4], bv[4];
#pragma unroll
            for (int j = 0; j < 4; j++) a[j] = Asm[k][ty * 4 + j];
#pragma unroll
            for (int j = 0; j < 4; j++) bv[j] = Bsm[k][tx * 4 + j];
#pragma unroll
            for (int i = 0; i < 4; i++)
#pragma unroll
                for (int j = 0; j < 4; j++) acc[i][j] += a[i] * bv[j];
        }
        __syncthreads();
    }
#pragma unroll
    for (int i = 0; i < 4; i++) {
        const int row = row0 + ty * 4 + i;
#pragma unroll
        for (int j = 0; j < 4; j++) {
            const int col = col0 + tx * 4 + j;
            out[(size_t)row * Nd + col] = __float2bfloat16(acc[i][j] + bias[col]);
        }
    }
}

__global__ __launch_bounds__(256) void fused_attn(
    const float* __restrict__ x, const float* __restrict__ adj,
    const float* __restrict__ W_theta, const float* __restrict__ b_theta,
    const bf16* __restrict__ phi, const bf16* __restrict__ g,
    const float* __restrict__ W_out, const float* __restrict__ b_out,
    float* __restrict__ out)
{
    __shared__ float xs[Cc];
    __shared__ float th[Dd];
    __shared__ float s[Nn];
    __shared__ float Os[Dd];
    __shared__ float red[256];
    const int tid = threadIdx.x;
    const int n = blockIdx.x, b = blockIdx.y;
    const int lane = tid & 63, wave = tid >> 6;
    const size_t row = (size_t)b * Nn + n;
    const size_t baseD = (size_t)b * Nn * Dd;
    for (int c = tid; c < Cc; c += 256) xs[c] = x[row * Cc + c];
    __syncthreads();
    for (int d = tid; d < Dd; d += 256) {
        float acc = b_theta[d];
#pragma unroll 8
        for (int c = 0; c < Cc; c++) acc += xs[c] * W_theta[(size_t)c * Dd + d];
        th[d] = acc;
    }
    __syncthreads();
    for (int m = wave; m < Nn; m += 4) {
        const bf16* prow = phi + baseD + (size_t)m * Dd;
        float partial = 0.f;
#pragma unroll
        for (int j = 0; j < 6; j++) {
            const int d = lane + 64 * j;
            partial += th[d] * b2f(prow[d]);
        }
#pragma unroll
        for (int off = 32; off > 0; off >>= 1) partial += __shfl_down(partial, off);
        if (lane == 0)
            s[m] = partial * adj[(size_t)b * Nn * Nn + (size_t)n * Nn + m];
    }
    __syncthreads();
    float mx = -1e30f;
    for (int i = tid; i < Nn; i += 256) mx = fmaxf(mx, s[i]);
    red[tid] = mx; __syncthreads();
    for (int st = 128; st > 0; st >>= 1) {
        if (tid < st) red[tid] = fmaxf(red[tid], red[tid + st]);
        __syncthreads();
    }
    mx = red[0]; __syncthreads();
    float lsum = 0.f;
    for (int i = tid; i < Nn; i += 256) {
        const float e = __expf(s[i] - mx);
        s[i] = e;
        lsum += e;
    }
    red[tid] = lsum; __syncthreads();
    for (int st = 128; st > 0; st >>= 1) {
        if (tid < st) red[tid] += red[tid + st];
        __syncthreads();
    }
    const float inv = 1.0f / red[0];
    __syncthreads();
    for (int d = tid; d < Dd; d += 256) {
        float acc = 0.f;
#pragma unroll 8
        for (int m = 0; m < Nn; m++) acc += s[m] * b2f(g[baseD + (size_t)m * Dd + d]);
        Os[d] = acc * inv;
    }
    __syncthreads();
    for (int c = tid; c < Cc; c += 256) {
        float acc = b_out[c] + xs[c];
#pragma unroll 8
        for (int d = 0; d < Dd; d++) acc += Os[d] * W_out[(size_t)d * Cc + c];
        out[row * Cc + c] = acc;
    }
}

// ============================== launcher ======================================
extern "C" void kernel_launch(void* const* d_in, const int* in_sizes, int n_in,
                              void* d_out, int out_size, void* d_ws, size_t ws_size,
                              hipStream_t stream)
{
    const float* x       = (const float*)d_in[0];
    const float* adj     = (const float*)d_in[1];
    const float* W_theta = (const float*)d_in[2];
    const float* b_theta = (const float*)d_in[3];
    const float* W_phi   = (const float*)d_in[4];
    const float* b_phi   = (const float*)d_in[5];
    const float* W_g     = (const float*)d_in[6];
    const float* b_g     = (const float*)d_in[7];
    const float* W_out   = (const float*)d_in[8];
    const float* b_out   = (const float*)d_in[9];
    float* out = (float*)d_out;

    const int M = Bb * Nn;                       // 16384
    const size_t SZ = (size_t)Bb * Nn * Dd;      // 6291456
    const size_t WSZ = (size_t)Cc * Dd;          // 294912
    const size_t NEED = (4 * WSZ + 4 * SZ) * sizeof(bf16);  // ~50.25 MiB

    dim3 blk(256);

    if (ws_size >= NEED) {
        bf16* WtT   = (bf16*)d_ws;          // [384][768]
        bf16* WpT   = WtT + WSZ;            // [384][768]
        bf16* WgT   = WpT + WSZ;            // [384][768]
        bf16* WoT   = WgT + WSZ;            // [768][384]
        bf16* theta = WoT + WSZ;            // [16384][384]
        bf16* phi   = theta + SZ;
        bf16* gT    = phi + SZ;             // [16][384][1024]
        bf16* O     = gT + SZ;              // [16384][384]

        // weight transposes (f32 -> bf16)
        transpose_cast<<<dim3(Dd / 32, Cc / 32), blk, 0, stream>>>(W_theta, WtT, Cc, Dd);
        transpose_cast<<<dim3(Dd / 32, Cc / 32), blk, 0, stream>>>(W_phi,   WpT, Cc, Dd);
        transpose_cast<<<dim3(Dd / 32, Cc / 32), blk, 0, stream>>>(W_g,     WgT, Cc, Dd);
        transpose_cast<<<dim3(Cc / 32, Dd / 32), blk, 0, stream>>>(W_out,   WoT, Dd, Cc);

        // projections [16384,768]@[768,384]
        dim3 gp(M / 128, Dd / 128);
        gemm_mfma<float, 0><<<gp, blk, 0, stream>>>(x, WtT, b_theta, nullptr, theta, Cc, Dd);
        gemm_mfma<float, 0><<<gp, blk, 0, stream>>>(x, WpT, b_phi,   nullptr, phi,   Cc, Dd);
        gemm_mfma<float, 1><<<gp, blk, 0, stream>>>(x, WgT, b_g,     nullptr, gT,    Cc, Dd);

        // attention
        flash_attn<<<dim3(Nn / 64, Bb), blk, 0, stream>>>(theta, phi, gT, adj, O);

        // out-projection + bias + residual -> f32
        dim3 go(M / 128, Cc / 128);
        gemm_mfma<bf16, 2><<<go, blk, 0, stream>>>(O, WoT, b_out, x, out, Dd, Cc);
    } else {
        // fallback (round-4 path, 25.2 MB ws)
        bf16* phi = (bf16*)d_ws;
        bf16* g   = phi + SZ;
        dim3 gproj(M / 64, Dd / 64);
        proj_gemm<<<gproj, blk, 0, stream>>>(x, W_phi, b_phi, phi, M, Cc, Dd);
        proj_gemm<<<gproj, blk, 0, stream>>>(x, W_g, b_g, g, M, Cc, Dd);
        fused_attn<<<dim3(Nn, Bb), blk, 0, stream>>>(
            x, adj, W_theta, b_theta, phi, g, W_out, b_out, out);
    }
}